// Round 1
// baseline (925.898 us; speedup 1.0000x reference)
//
#include <hip/hip_runtime.h>
#include <math.h>

// st_VQEmbedding: z_e_x [B=16,N=4096,D=64] f32, embedding [K=512,D=64] f32
// out [B,N,D] f32 = embedding[argmin_k ||x - e_k||^2] computed as
// (x2 - 2*dot) + e2 in fp32 (faithful to reference rounding), first-index
// tie-break, then straight-through output (q + x) - x.

constexpr int K = 512;
constexpr int D = 64;
constexpr int NPTS = 16 * 4096;     // 65536 points
constexpr int SPLIT = 4;            // threads per point
constexpr int KCHUNK = K / SPLIT;   // 128 codes per thread
constexpr int BLOCK = 256;

__global__ __launch_bounds__(BLOCK)
void vq_st_kernel(const float* __restrict__ z,
                  const float* __restrict__ emb,
                  float* __restrict__ out) {
    __shared__ float e2s[K];

    const int t = threadIdx.x;

    // Stage e2[k] = sum_d fl(e_kd^2), sequential, UNFUSED (matches jnp.sum(w*w))
    {
        #pragma clang fp contract(off)
        for (int k = t; k < K; k += BLOCK) {
            const float4* row = reinterpret_cast<const float4*>(emb + k * D);
            float s = 0.0f;
            #pragma unroll
            for (int i = 0; i < D / 4; ++i) {
                float4 v = row[i];
                s = s + v.x * v.x;
                s = s + v.y * v.y;
                s = s + v.z * v.z;
                s = s + v.w * v.w;
            }
            e2s[k] = s;
        }
    }
    __syncthreads();

    const int g   = blockIdx.x * BLOCK + t;
    const int pt  = g >> 2;        // point index
    const int sub = g & 3;         // k-subset

    // Load full x row into registers (64 floats = 16 float4)
    const float4* xrow = reinterpret_cast<const float4*>(z + pt * D);
    float4 x[16];
    #pragma unroll
    for (int i = 0; i < 16; ++i) x[i] = xrow[i];

    // x2 = sum_d fl(x_d^2), sequential, UNFUSED
    float x2 = 0.0f;
    {
        #pragma clang fp contract(off)
        #pragma unroll
        for (int i = 0; i < 16; ++i) {
            x2 = x2 + x[i].x * x[i].x;
            x2 = x2 + x[i].y * x[i].y;
            x2 = x2 + x[i].z * x[i].z;
            x2 = x2 + x[i].w * x[i].w;
        }
    }

    const int k0 = sub * KCHUNK;
    float best = INFINITY;
    int   bidx = 0;

    for (int kk = 0; kk < KCHUNK; kk += 4) {
        const float4* r0 = reinterpret_cast<const float4*>(emb + (k0 + kk + 0) * D);
        const float4* r1 = reinterpret_cast<const float4*>(emb + (k0 + kk + 1) * D);
        const float4* r2 = reinterpret_cast<const float4*>(emb + (k0 + kk + 2) * D);
        const float4* r3 = reinterpret_cast<const float4*>(emb + (k0 + kk + 3) * D);

        float a0 = 0.0f, a1 = 0.0f, a2 = 0.0f, a3 = 0.0f;
        #pragma unroll
        for (int i = 0; i < 16; ++i) {
            float4 e0 = r0[i], e1 = r1[i], e2v = r2[i], e3 = r3[i];
            float4 xv = x[i];
            a0 = __builtin_fmaf(xv.x, e0.x, a0);
            a0 = __builtin_fmaf(xv.y, e0.y, a0);
            a0 = __builtin_fmaf(xv.z, e0.z, a0);
            a0 = __builtin_fmaf(xv.w, e0.w, a0);
            a1 = __builtin_fmaf(xv.x, e1.x, a1);
            a1 = __builtin_fmaf(xv.y, e1.y, a1);
            a1 = __builtin_fmaf(xv.z, e1.z, a1);
            a1 = __builtin_fmaf(xv.w, e1.w, a1);
            a2 = __builtin_fmaf(xv.x, e2v.x, a2);
            a2 = __builtin_fmaf(xv.y, e2v.y, a2);
            a2 = __builtin_fmaf(xv.z, e2v.z, a2);
            a2 = __builtin_fmaf(xv.w, e2v.w, a2);
            a3 = __builtin_fmaf(xv.x, e3.x, a3);
            a3 = __builtin_fmaf(xv.y, e3.y, a3);
            a3 = __builtin_fmaf(xv.z, e3.z, a3);
            a3 = __builtin_fmaf(xv.w, e3.w, a3);
        }

        // dist = (x2 - 2*dot) + e2   (2*dot exact => fma-vs-sub identical)
        float d0 = (x2 - 2.0f * a0) + e2s[k0 + kk + 0];
        float d1 = (x2 - 2.0f * a1) + e2s[k0 + kk + 1];
        float d2 = (x2 - 2.0f * a2) + e2s[k0 + kk + 2];
        float d3 = (x2 - 2.0f * a3) + e2s[k0 + kk + 3];

        // first-index argmin: strict < keeps earliest
        if (d0 < best) { best = d0; bidx = k0 + kk + 0; }
        if (d1 < best) { best = d1; bidx = k0 + kk + 1; }
        if (d2 < best) { best = d2; bidx = k0 + kk + 2; }
        if (d3 < best) { best = d3; bidx = k0 + kk + 3; }
    }

    // Combine across the 4 lanes of this point: lexicographic (dist, idx) min
    #pragma unroll
    for (int off = 1; off < 4; off <<= 1) {
        float ob = __shfl_xor(best, off, 4);
        int   oi = __shfl_xor(bidx, off, 4);
        if (ob < best || (ob == best && oi < bidx)) { best = ob; bidx = oi; }
    }

    // Output: lane `sub` writes dims [sub*16, sub*16+16).
    // Straight-through faithful: out = (q + x) - x  (no fast-math reassociation at -O3)
    const float4* qrow = reinterpret_cast<const float4*>(emb + bidx * D);
    float4*       orow = reinterpret_cast<float4*>(out + pt * D);
    #pragma unroll
    for (int i = 0; i < 4; ++i) {
        const int idx = sub * 4 + i;
        float4 q  = qrow[idx];
        float4 xv = x[idx];
        float4 o;
        o.x = (q.x + xv.x) - xv.x;
        o.y = (q.y + xv.y) - xv.y;
        o.z = (q.z + xv.z) - xv.z;
        o.w = (q.w + xv.w) - xv.w;
        orow[idx] = o;
    }
}

extern "C" void kernel_launch(void* const* d_in, const int* in_sizes, int n_in,
                              void* d_out, int out_size, void* d_ws, size_t ws_size,
                              hipStream_t stream) {
    const float* z   = (const float*)d_in[0];   // [B,N,D] f32
    const float* emb = (const float*)d_in[1];   // [K,D] f32
    float* out = (float*)d_out;                  // [B,N,D] f32

    const int total_threads = NPTS * SPLIT;      // 262144
    const int grid = total_threads / BLOCK;      // 1024
    vq_st_kernel<<<grid, BLOCK, 0, stream>>>(z, emb, out);
}

// Round 2
// 84.064 us; speedup vs baseline: 11.0142x; 11.0142x over previous
//
#include <hip/hip_runtime.h>
#include <math.h>

// st_VQEmbedding: z [B=16,N=4096,D=64] f32, emb [K=512,D=64] f32
// out = emb[argmin_k (x2 - 2*x.e_k) + e2_k], straight-through (q+x)-x.
// Bit-exact vs round-1 passing kernel: same FMA chains, same scan order,
// same tie-break (strict <, ascending k, lexicographic cross-sub combine).

constexpr int K      = 512;
constexpr int D      = 64;           // 16 float4 per row
constexpr int NPTS   = 16 * 4096;    // 65536 points
constexpr int BLOCK  = 256;
constexpr int SPLIT  = 4;            // 4 subs share one point-pair
constexpr int TILE_C = 32;           // codes per sub per LDS tile
constexpr int NTILES = (K / SPLIT) / TILE_C;   // 4
constexpr int PPB    = 128;          // points per block (64 pairs)

__global__ __launch_bounds__(BLOCK, 2)
void vq_st_kernel(const float* __restrict__ z,
                  const float* __restrict__ emb,
                  float* __restrict__ out)
{
    // LDS tile layout (float4 slots): f = c*64 + j*4 + s
    //   s = sub (0..3), j = dim-chunk (0..15), c = code-in-tile (0..31)
    // -> per ds_read_b128 instruction the 4 subs hit 4 consecutive 16B slots
    //    (distinct bank quartets, broadcast to 16 lanes each): conflict-free,
    //    and j becomes a compile-time ds_read offset immediate.
    __shared__ float4 buf[2][2048];   // 2 x 32 KiB
    __shared__ float  e2s[K];         // 2 KiB
    __shared__ int    bidx_s[PPB];    // 0.5 KiB

    const int tid  = threadIdx.x;
    const int w    = tid >> 6;        // wave 0..3
    const int lane = tid & 63;
    const int pr   = tid >> 2;        // pair 0..63
    const int sub  = tid & 3;

    const float4* ef4 = reinterpret_cast<const float4*>(emb);
    const float4* zf4 = reinterpret_cast<const float4*>(z);
    float4*       of4 = reinterpret_cast<float4*>(out);

    const int base = blockIdx.x * PPB;
    const int pt0  = base + pr * 2;
    const int pt1  = pt0 + 1;

    // ---- async stage of one 32-code-per-sub tile into buf[b] ----
    auto stage = [&](int tt, int b) {
        #pragma unroll
        for (int i = 0; i < 8; ++i) {
            const int f = (w * 8 + i) * 64 + lane;   // lane-linear LDS slot
            const int s = f & 3;
            const int j = (f >> 2) & 15;
            const int c = f >> 6;
            const float4* src = ef4 + ((s * 128 + tt * TILE_C + c) * 16 + j);
            __builtin_amdgcn_global_load_lds(
                (const __attribute__((address_space(1))) void*)src,
                (__attribute__((address_space(3))) void*)&buf[b][f],
                16, 0, 0);
        }
    };

    stage(0, 0);   // tile 0 in flight during e2/x setup

    // ---- e2[k] = sum_d fl(e_kd^2), sequential, unfused (matches jnp) ----
    {
        #pragma clang fp contract(off)
        #pragma unroll
        for (int kk = 0; kk < K / BLOCK; ++kk) {
            const int k = tid + kk * BLOCK;
            const float4* row = ef4 + k * 16;
            float s = 0.0f;
            #pragma unroll
            for (int i = 0; i < 16; ++i) {
                float4 v = row[i];
                s = s + v.x * v.x;
                s = s + v.y * v.y;
                s = s + v.z * v.z;
                s = s + v.w * v.w;
            }
            e2s[k] = s;
        }
    }

    // ---- x rows for this thread's two points, kept in VGPRs ----
    float4 x0[16], x1[16];
    #pragma unroll
    for (int i = 0; i < 16; ++i) x0[i] = zf4[pt0 * 16 + i];
    #pragma unroll
    for (int i = 0; i < 16; ++i) x1[i] = zf4[pt1 * 16 + i];

    float x2_0 = 0.0f, x2_1 = 0.0f;
    {
        #pragma clang fp contract(off)
        #pragma unroll
        for (int i = 0; i < 16; ++i) {
            x2_0 = x2_0 + x0[i].x * x0[i].x;
            x2_0 = x2_0 + x0[i].y * x0[i].y;
            x2_0 = x2_0 + x0[i].z * x0[i].z;
            x2_0 = x2_0 + x0[i].w * x0[i].w;
        }
        #pragma unroll
        for (int i = 0; i < 16; ++i) {
            x2_1 = x2_1 + x1[i].x * x1[i].x;
            x2_1 = x2_1 + x1[i].y * x1[i].y;
            x2_1 = x2_1 + x1[i].z * x1[i].z;
            x2_1 = x2_1 + x1[i].w * x1[i].w;
        }
    }

    __syncthreads();   // drains vmcnt: buf[0] + e2s ready

    float best0 = INFINITY, best1 = INFINITY;
    int   bi0 = 0, bi1 = 0;
    int   cur = 0;

    for (int t = 0; t < NTILES; ++t) {
        if (t + 1 < NTILES) stage(t + 1, cur ^ 1);

        const float4* cb   = &buf[cur][sub];
        const int     kb   = sub * (K / SPLIT) + t * TILE_C;

        for (int c = 0; c < TILE_C; ++c) {
            const float4* er = cb + c * 64;
            float a0 = 0.0f, a1 = 0.0f;
            #pragma unroll
            for (int j = 0; j < 16; ++j) {
                float4 e = er[j * 4];
                a0 = __builtin_fmaf(x0[j].x, e.x, a0);
                a0 = __builtin_fmaf(x0[j].y, e.y, a0);
                a0 = __builtin_fmaf(x0[j].z, e.z, a0);
                a0 = __builtin_fmaf(x0[j].w, e.w, a0);
                a1 = __builtin_fmaf(x1[j].x, e.x, a1);
                a1 = __builtin_fmaf(x1[j].y, e.y, a1);
                a1 = __builtin_fmaf(x1[j].z, e.z, a1);
                a1 = __builtin_fmaf(x1[j].w, e.w, a1);
            }
            const int   k   = kb + c;
            const float e2v = e2s[k];
            const float d0  = (x2_0 - 2.0f * a0) + e2v;
            const float d1  = (x2_1 - 2.0f * a1) + e2v;
            if (d0 < best0) { best0 = d0; bi0 = k; }
            if (d1 < best1) { best1 = d1; bi1 = k; }
        }
        __syncthreads();   // drains my stage loads; all waves done with buf[cur]
        cur ^= 1;
    }

    // ---- combine the 4 subs of each pair: lexicographic (dist, idx) min ----
    #pragma unroll
    for (int off = 1; off < 4; off <<= 1) {
        float ob = __shfl_xor(best0, off, 4);
        int   oi = __shfl_xor(bi0,   off, 4);
        if (ob < best0 || (ob == best0 && oi < bi0)) { best0 = ob; bi0 = oi; }
        ob = __shfl_xor(best1, off, 4);
        oi = __shfl_xor(bi1,   off, 4);
        if (ob < best1 || (ob == best1 && oi < bi1)) { best1 = ob; bi1 = oi; }
    }
    if (sub == 0) {
        bidx_s[pr * 2]     = bi0;
        bidx_s[pr * 2 + 1] = bi1;
    }
    __syncthreads();

    // ---- dense epilogue: lane-linear float4 stores (full cache lines) ----
    #pragma unroll
    for (int i = 0; i < 8; ++i) {
        const int idx = i * BLOCK + tid;       // f4 slot in block's 128 rows
        const int p   = idx >> 4;
        const int j   = idx & 15;
        const float4 q  = ef4[bidx_s[p] * 16 + j];
        const float4 xv = zf4[(base + p) * 16 + j];
        float4 o;
        o.x = (q.x + xv.x) - xv.x;
        o.y = (q.y + xv.y) - xv.y;
        o.z = (q.z + xv.z) - xv.z;
        o.w = (q.w + xv.w) - xv.w;
        of4[(base + p) * 16 + j] = o;
    }
}

extern "C" void kernel_launch(void* const* d_in, const int* in_sizes, int n_in,
                              void* d_out, int out_size, void* d_ws, size_t ws_size,
                              hipStream_t stream) {
    const float* z   = (const float*)d_in[0];
    const float* emb = (const float*)d_in[1];
    float* out = (float*)d_out;

    const int grid = NPTS / PPB;   // 512 blocks, 2 per CU
    vq_st_kernel<<<grid, BLOCK, 0, stream>>>(z, emb, out);
}